// Round 7
// baseline (13.836 us; speedup 1.0000x reference)
//
#include <hip/hip_runtime.h>

#define BB 8
#define NN 4096
#define KK 2048
#define C4 64   // C/4 float4 per row

// 2048 blocks x 256 threads (4 waves); each block owns 16 consecutive output
// rows of one batch; each wave owns 4 rows. 8 blocks/CU -> fine-grained
// barrier groups that interleave across each other's stalls.
// Phase 0 (no deps): each wave reads its own 4 idx values (one broadcast int4)
//   and immediately stores zeros for its unselected rows.
// Phase 1: cooperative reduce of idx[b, 0:rowStart) (<=4 int4/thread,
//   independent loads) for the global base; per-wave 4-sums into LDS.
// Phase 2: copy selected rows from x.
__global__ __launch_bounds__(256) void topk_fused_kernel(const float4* __restrict__ x,
                                                         const int* __restrict__ idx,
                                                         float4* __restrict__ out) {
    const int bi = blockIdx.x;               // 0..2047
    const int b = bi >> 8;                   // 256 blocks per batch
    const int rowStart = (bi & 255) << 4;    // 16 rows per block
    const int t = threadIdx.x;
    const int lane = t & 63;
    const int wave = t >> 6;                 // 0..3

    const int4* idxB4 = (const int4*)(idx + (size_t)b * NN);

    // ---- phase 0: this wave's 4 idx values; store zeros now (no deps) ----
    const int4 v4 = idxB4[(rowStart >> 2) + wave];     // wave-uniform broadcast
    const long long outRow0 = (long long)b * NN + rowStart + wave * 4;
    const float4 z = make_float4(0.f, 0.f, 0.f, 0.f);
    if (v4.x <= 0) out[(outRow0 + 0) * C4 + lane] = z;
    if (v4.y <= 0) out[(outRow0 + 1) * C4 + lane] = z;
    if (v4.z <= 0) out[(outRow0 + 2) * C4 + lane] = z;
    if (v4.w <= 0) out[(outRow0 + 3) * C4 + lane] = z;

    // ---- phase 1: base reduce (idx[0:rowStart)) + per-wave 4-sums ----
    __shared__ int waveSum[4];    // partial sums of idx[0:rowStart)
    __shared__ int waveLoc[4];    // each wave's sum of its own 4 idx values

    int partial = 0;
    const int n4 = rowStart >> 2;            // <= 1020
#pragma unroll
    for (int i = 0; i < 4; ++i) {
        const int j = t + i * 256;
        if (j < n4) {
            const int4 v = idxB4[j];
            partial += v.x + v.y + v.z + v.w;
        }
    }
#pragma unroll
    for (int off = 32; off > 0; off >>= 1)
        partial += __shfl_down(partial, off, 64);
    if (lane == 0) {
        waveSum[wave] = partial;
        waveLoc[wave] = v4.x + v4.y + v4.z + v4.w;
    }
    __syncthreads();

    const int4 s = *(const int4*)waveSum;
    const int base = s.x + s.y + s.z + s.w;
    int preW = 0;
    for (int w = 0; w < wave; ++w) preW += waveLoc[w];

    // ---- phase 2: copy selected rows ----
    long long r = (long long)b * KK + base + preW;   // rank of 1st selected row here
    if (v4.x > 0) { out[(outRow0 + 0) * C4 + lane] = x[r * C4 + lane]; r += 1; }
    if (v4.y > 0) { out[(outRow0 + 1) * C4 + lane] = x[r * C4 + lane]; r += 1; }
    if (v4.z > 0) { out[(outRow0 + 2) * C4 + lane] = x[r * C4 + lane]; r += 1; }
    if (v4.w > 0) { out[(outRow0 + 3) * C4 + lane] = x[r * C4 + lane]; }
}

extern "C" void kernel_launch(void* const* d_in, const int* in_sizes, int n_in,
                              void* d_out, int out_size, void* d_ws, size_t ws_size,
                              hipStream_t stream) {
    const float* x  = (const float*)d_in[0];   // (B, K, C) float32
    const int* idx  = (const int*)d_in[1];     // (B, N) int32
    // d_in[2] = A (B, N, N) -- only its shape matters; never read.
    float* out = (float*)d_out;                // (B, N, C) float32

    topk_fused_kernel<<<(BB * NN) / 16, 256, 0, stream>>>(
        (const float4*)x, idx, (float4*)out);
}

// Round 8
// 13.455 us; speedup vs baseline: 1.0283x; 1.0283x over previous
//
#include <hip/hip_runtime.h>

#define BB 8
#define NN 4096
#define KK 2048
#define C4 64   // C/4 float4 per row

// 2048 blocks x 256 threads (4 waves); each block owns 16 consecutive output
// rows of one batch; each wave owns 4 rows.
// Phase 0 (no deps): each wave reads its own 4 idx values (one broadcast int4)
//   and immediately stores zeros for its unselected rows.
// Phase 1: cooperative reduce of idx[b, 0:rowStart) for the global base.
// Phase 2: LOAD-ALL-THEN-STORE-ALL gather -- all 4 x-loads issued before any
//   store so their L2/L3 latencies overlap (R7 exposed them serially).
__global__ __launch_bounds__(256) void topk_fused_kernel(const float4* __restrict__ x,
                                                         const int* __restrict__ idx,
                                                         float4* __restrict__ out) {
    const int bi = blockIdx.x;               // 0..2047
    const int b = bi >> 8;                   // 256 blocks per batch
    const int rowStart = (bi & 255) << 4;    // 16 rows per block
    const int t = threadIdx.x;
    const int lane = t & 63;
    const int wave = t >> 6;                 // 0..3

    const int4* idxB4 = (const int4*)(idx + (size_t)b * NN);

    // ---- phase 0: this wave's 4 idx values; store zeros now (no deps) ----
    const int4 v4 = idxB4[(rowStart >> 2) + wave];     // wave-uniform broadcast
    const long long outRow0 = (long long)b * NN + rowStart + wave * 4;
    const float4 z = make_float4(0.f, 0.f, 0.f, 0.f);
    if (v4.x <= 0) out[(outRow0 + 0) * C4 + lane] = z;
    if (v4.y <= 0) out[(outRow0 + 1) * C4 + lane] = z;
    if (v4.z <= 0) out[(outRow0 + 2) * C4 + lane] = z;
    if (v4.w <= 0) out[(outRow0 + 3) * C4 + lane] = z;

    // ---- phase 1: base reduce (idx[0:rowStart)) + per-wave 4-sums ----
    __shared__ int waveSum[4];    // partial sums of idx[0:rowStart)
    __shared__ int waveLoc[4];    // each wave's sum of its own 4 idx values

    int partial = 0;
    const int n4 = rowStart >> 2;            // <= 1020
#pragma unroll
    for (int i = 0; i < 4; ++i) {
        const int j = t + i * 256;
        if (j < n4) {
            const int4 v = idxB4[j];
            partial += v.x + v.y + v.z + v.w;
        }
    }
#pragma unroll
    for (int off = 32; off > 0; off >>= 1)
        partial += __shfl_down(partial, off, 64);
    if (lane == 0) {
        waveSum[wave] = partial;
        waveLoc[wave] = v4.x + v4.y + v4.z + v4.w;
    }
    __syncthreads();

    const int4 s = *(const int4*)waveSum;
    int preW = 0;
    for (int w = 0; w < wave; ++w) preW += waveLoc[w];
    const long long r0 = (long long)b * KK + (s.x + s.y + s.z + s.w) + preW;

    // ---- phase 2: independent ranks; issue all loads, then all stores ----
    const long long r1 = r0 + (v4.x > 0 ? 1 : 0);
    const long long r2 = r1 + (v4.y > 0 ? 1 : 0);
    const long long r3 = r2 + (v4.z > 0 ? 1 : 0);

    float4 val0, val1, val2, val3;
    if (v4.x > 0) val0 = x[r0 * C4 + lane];
    if (v4.y > 0) val1 = x[r1 * C4 + lane];
    if (v4.z > 0) val2 = x[r2 * C4 + lane];
    if (v4.w > 0) val3 = x[r3 * C4 + lane];

    if (v4.x > 0) out[(outRow0 + 0) * C4 + lane] = val0;
    if (v4.y > 0) out[(outRow0 + 1) * C4 + lane] = val1;
    if (v4.z > 0) out[(outRow0 + 2) * C4 + lane] = val2;
    if (v4.w > 0) out[(outRow0 + 3) * C4 + lane] = val3;
}

extern "C" void kernel_launch(void* const* d_in, const int* in_sizes, int n_in,
                              void* d_out, int out_size, void* d_ws, size_t ws_size,
                              hipStream_t stream) {
    const float* x  = (const float*)d_in[0];   // (B, K, C) float32
    const int* idx  = (const int*)d_in[1];     // (B, N) int32
    // d_in[2] = A (B, N, N) -- only its shape matters; never read.
    float* out = (float*)d_out;                // (B, N, C) float32

    topk_fused_kernel<<<(BB * NN) / 16, 256, 0, stream>>>(
        (const float4*)x, idx, (float4*)out);
}